// Round 6
// baseline (186.035 us; speedup 1.0000x reference)
//
#include <hip/hip_runtime.h>

#define NNODES 15279
#define NEDGE  488928
#define INCH   1024
#define NHID   512
#define NCLS   16
#define EMBROWS 10001

using short8 = __attribute__((ext_vector_type(8))) short;
using f32x4  = __attribute__((ext_vector_type(4))) float;
using f32x2  = __attribute__((ext_vector_type(2))) float;

__device__ __forceinline__ float bf2f(unsigned short u) {
  union { unsigned int i; float f; } v; v.i = ((unsigned int)u) << 16; return v.f;
}
__device__ __forceinline__ float asf(unsigned int u) {
  union { unsigned int i; float f; } v; v.i = u; return v.f;
}
__device__ __forceinline__ unsigned short f2bf(float f) {
  union { float ff; unsigned int i; } v; v.ff = f;
  return (unsigned short)((v.i + 0x7FFFu + ((v.i >> 16) & 1u)) >> 16);
}

// ---------- relu(emb_table) -> bf16 embr [EMBROWS][128] ----------
__global__ __launch_bounds__(256) void k_embr(const float* __restrict__ emb,
                                              unsigned short* __restrict__ embr) {
  int g = blockIdx.x * 256 + threadIdx.x;          // granule of 4 floats
  if (g * 4 >= EMBROWS * 128) return;
  const float4 v = *(const float4*)&emb[g * 4];
  unsigned int lo = (unsigned int)f2bf(fmaxf(v.x, 0.f)) | ((unsigned int)f2bf(fmaxf(v.y, 0.f)) << 16);
  unsigned int hi = (unsigned int)f2bf(fmaxf(v.z, 0.f)) | ((unsigned int)f2bf(fmaxf(v.w, 0.f)) << 16);
  uint2 o; o.x = lo; o.y = hi;
  *(uint2*)&embr[g * 4] = o;
}

// ---------- W1 [INCH][NHID] fp32 -> w1t [NHID][INCH] bf16 ----------
__global__ __launch_bounds__(256) void k_w1t(const float* __restrict__ W1,
                                             unsigned short* __restrict__ w1t) {
  __shared__ float tile[64][65];
  int k0 = blockIdx.x * 64, n0 = blockIdx.y * 64;
  int t = threadIdx.x;
  int c = t & 63, r4 = t >> 6;
  for (int i = 0; i < 16; ++i) {
    int r = r4 + i * 4;
    tile[r][c] = W1[(k0 + r) * NHID + n0 + c];
  }
  __syncthreads();
  for (int i = 0; i < 16; ++i) {
    int nr = r4 + i * 4;
    w1t[(size_t)(n0 + nr) * INCH + k0 + c] = f2bf(tile[c][nr]);
  }
}

// ---------- CSR build ----------
__global__ __launch_bounds__(256) void k_hist(const int* __restrict__ rows,
                                              int* __restrict__ counts) {
  int e = blockIdx.x * 256 + threadIdx.x;
  if (e < NEDGE) atomicAdd(&counts[rows[e]], 1);
}

__global__ __launch_bounds__(256) void k_scan(const int* __restrict__ counts,
                                              int* __restrict__ rs) {
  int t = threadIdx.x;
  int lo = t * 60, hi = lo + 60;
  if (hi > NNODES) hi = NNODES;
  if (lo > NNODES) lo = NNODES;
  int s = 0;
  for (int i = lo; i < hi; ++i) s += counts[i];
  int lane = t & 63, wid = t >> 6;
  int v = s;
  for (int d = 1; d < 64; d <<= 1) {
    int u = __shfl_up(v, d);
    if (lane >= d) v += u;
  }
  __shared__ int wsum[4];
  if (lane == 63) wsum[wid] = v;
  __syncthreads();
  int wbase = 0;
  for (int w2 = 0; w2 < wid; ++w2) wbase += wsum[w2];
  int run = wbase + v - s;
  for (int i = lo; i < hi; ++i) { rs[i] = run; run += counts[i]; }
  if (t == 255) rs[NNODES] = run;
}

__global__ __launch_bounds__(256) void k_scatter(const int* __restrict__ rows,
                                                 const int* __restrict__ cols,
                                                 const float* __restrict__ vals,
                                                 const int* __restrict__ rs,
                                                 int* __restrict__ cursor,
                                                 int* __restrict__ scol,
                                                 int* __restrict__ scolb,
                                                 float* __restrict__ sval) {
  int e = blockIdx.x * 256 + threadIdx.x;
  if (e < NEDGE) {
    int r = rows[e];
    int p = rs[r] + atomicAdd(&cursor[r], 1);
    int c = cols[e];
    scol[p] = c;
    scolb[p] = c * 128;      // byte offset into a 64-wide bf16 slice row
    sval[p] = vals[e];
  }
}

// ---------- GEMM1: t1s = relu(emb[x]) @ W1, A staged from embr via x-indirection ----------
// s = kt>>1 (embedding slot, constant per K-tile), d = (kt&1)*64 + granule*8.
// Output SLICE-MAJOR t1s[8][NNODES][64].
__global__ __launch_bounds__(256) void k_gemm1(const int* __restrict__ x,
                                               const unsigned short* __restrict__ embr,
                                               const unsigned short* __restrict__ Bt,
                                               unsigned short* __restrict__ Cs) {
  __shared__ unsigned short As[128 * 64];
  __shared__ unsigned short Bs[128 * 64];
  const int t = threadIdx.x;
  const int m0 = (blockIdx.x >> 2) * 128;
  const int n0 = (blockIdx.x & 3) * 128;
  const int w = t >> 6, l = t & 63;
  const int wm = w >> 1, wn = w & 1;
  const int l4 = l >> 4, l15 = l & 15;
  const int rowA = wm * 64 + l15;
  const int colB = wn * 64 + l15;
  f32x4 acc[4][4] = {};

  for (int kt = 0; kt < 16; ++kt) {
    const int k0 = kt * 64;
    const int s = kt >> 1;
    const int dbase = (kt & 1) * 64;
#pragma unroll
    for (int i = 0; i < 4; ++i) {
      int p = i * 256 + t;
      int row = p >> 3, kg = p & 7;
      int skg = (kg ^ (row & 7)) * 8;
      int ga = m0 + row; ga = ga < NNODES ? ga : NNODES - 1;
      int idx = x[ga * 8 + s];
      __builtin_amdgcn_global_load_lds(
          (const __attribute__((address_space(1))) void*)&embr[(size_t)idx * 128 + dbase + skg],
          (__attribute__((address_space(3))) void*)&As[p * 8], 16, 0, 0);
      __builtin_amdgcn_global_load_lds(
          (const __attribute__((address_space(1))) void*)&Bt[(size_t)(n0 + row) * INCH + k0 + skg],
          (__attribute__((address_space(3))) void*)&Bs[p * 8], 16, 0, 0);
    }
    __syncthreads();
    for (int kk = 0; kk < 2; ++kk) {
      short8 af[4], bfr[4];
      for (int m = 0; m < 4; ++m) {
        int r = rowA + m * 16;
        af[m] = *(const short8*)&As[(r * 8 + ((kk * 4 + l4) ^ (r & 7))) * 8];
      }
      for (int n = 0; n < 4; ++n) {
        int c = colB + n * 16;
        bfr[n] = *(const short8*)&Bs[(c * 8 + ((kk * 4 + l4) ^ (c & 7))) * 8];
      }
      for (int m = 0; m < 4; ++m)
        for (int n = 0; n < 4; ++n)
          acc[m][n] = __builtin_amdgcn_mfma_f32_16x16x32_bf16(af[m], bfr[n], acc[m][n], 0, 0, 0);
    }
    __syncthreads();
  }
  const int rb = m0 + wm * 64 + l4 * 4;
  const int cb = n0 + wn * 64 + l15;
  for (int m = 0; m < 4; ++m)
    for (int j = 0; j < 4; ++j) {
      int r = rb + m * 16 + j;
      if (r < NNODES)
        for (int n = 0; n < 4; ++n) {
          int c = cb + n * 16;
          Cs[((size_t)(c >> 6) * NNODES + r) * 64 + (c & 63)] = f2bf(acc[m][n][j]);
        }
    }
}

// ---------- spmm1 + bias + relu, feature-sliced, 8 rows/warp (no reduce) ----------
// blockIdx&7 = slice (round-robin XCD dispatch -> slice stays in one 4MB L2).
// lane: rloc=l>>3 (row 0..7), ft=l&7 (8 bf16 feats = 16B gather). Unroll x2.
__global__ __launch_bounds__(256) void k_spmm1(const int* __restrict__ rs,
                                               const int* __restrict__ scolb,
                                               const float* __restrict__ sval,
                                               const unsigned short* __restrict__ t1s,
                                               const float* __restrict__ b1,
                                               unsigned short* __restrict__ h1) {
  int b = blockIdx.x;
  int slice = b & 7;
  int rgrp = b >> 3;
  int t = threadIdx.x;
  int wid = t >> 6, lane = t & 63;
  int rloc = lane >> 3, ft = lane & 7;
  int r = rgrp * 32 + wid * 8 + rloc;
  bool valid = r < NNODES;
  int rr = valid ? r : NNODES - 1;
  const char* tbase = (const char*)(t1s + (size_t)slice * NNODES * 64) + ft * 16;
  int fglob = slice * 64 + ft * 8;
  int e0 = rs[rr];
  int e1 = valid ? rs[rr + 1] : e0;
  f32x2 acc[4] = {};
  int e = e0;
  for (; e + 1 < e1; e += 2) {
    int cA = scolb[e], cB = scolb[e + 1];
    float vA = sval[e], vB = sval[e + 1];
    uint4 a  = *(const uint4*)(tbase + (size_t)(unsigned)cA);
    uint4 bq = *(const uint4*)(tbase + (size_t)(unsigned)cB);
    f32x2 vA2 = {vA, vA}, vB2 = {vB, vB};
    unsigned int ua[4] = {a.x, a.y, a.z, a.w};
    unsigned int ub[4] = {bq.x, bq.y, bq.z, bq.w};
#pragma unroll
    for (int d = 0; d < 4; ++d) {
      f32x2 pa = {asf(ua[d] << 16), asf(ua[d] & 0xffff0000u)};
      f32x2 pb = {asf(ub[d] << 16), asf(ub[d] & 0xffff0000u)};
      acc[d] += vA2 * pa;
      acc[d] += vB2 * pb;
    }
  }
  if (e < e1) {
    int c = scolb[e];
    float v = sval[e];
    uint4 a = *(const uint4*)(tbase + (size_t)(unsigned)c);
    f32x2 v2 = {v, v};
    unsigned int ua[4] = {a.x, a.y, a.z, a.w};
#pragma unroll
    for (int d = 0; d < 4; ++d) {
      f32x2 p = {asf(ua[d] << 16), asf(ua[d] & 0xffff0000u)};
      acc[d] += v2 * p;
    }
  }
  if (valid) {
    unsigned int o[4];
#pragma unroll
    for (int d = 0; d < 4; ++d) {
      float s0 = fmaxf(acc[d].x + b1[fglob + 2 * d], 0.f);
      float s1 = fmaxf(acc[d].y + b1[fglob + 2 * d + 1], 0.f);
      o[d] = (unsigned int)f2bf(s0) | ((unsigned int)f2bf(s1) << 16);
    }
    uint4 ov; ov.x = o[0]; ov.y = o[1]; ov.z = o[2]; ov.w = o[3];
    *(uint4*)&h1[(size_t)r * NHID + fglob] = ov;
  }
}

// ---------- GEMM2: t2 = h1 @ W2  (MFMA 16x16x32) ----------
__global__ __launch_bounds__(256) void k_gemm2(const unsigned short* __restrict__ h1,
                                               const float* __restrict__ W2,
                                               float* __restrict__ t2) {
  __shared__ unsigned short w2t[16 * 520];
  int t = threadIdx.x;
#pragma unroll
  for (int i = 0; i < 32; ++i) {
    int p = i * 256 + t;
    int k = p >> 4, f = p & 15;
    w2t[f * 520 + k] = f2bf(W2[p]);
  }
  __syncthreads();
  int w = t >> 6, l = t & 63;
  int l15 = l & 15, l4 = l >> 4;
  int r0 = blockIdx.x * 64 + w * 16;
  int row = r0 + l15; row = row < NNODES ? row : NNODES - 1;
  f32x4 acc = {};
#pragma unroll
  for (int kk = 0; kk < 16; ++kk) {
    short8 af = *(const short8*)&h1[(size_t)row * NHID + kk * 32 + l4 * 8];
    short8 bfr = *(const short8*)&w2t[l15 * 520 + kk * 32 + l4 * 8];
    acc = __builtin_amdgcn_mfma_f32_16x16x32_bf16(af, bfr, acc, 0, 0, 0);
  }
#pragma unroll
  for (int j = 0; j < 4; ++j) {
    int r = r0 + l4 * 4 + j;
    if (r < NNODES) t2[(size_t)r * NCLS + l15] = acc[j];
  }
}

// ---------- spmm2 + bias, unroll x4 ----------
__global__ __launch_bounds__(256) void k_spmm2(const int* __restrict__ rs,
                                               const int* __restrict__ scol,
                                               const float* __restrict__ sval,
                                               const float* __restrict__ t2,
                                               const float* __restrict__ b2,
                                               float* __restrict__ out) {
  int t = threadIdx.x;
  int f = t & 15, rl = t >> 4;
  int r = blockIdx.x * 16 + rl;
  if (r >= NNODES) return;
  int e0 = rs[r], e1 = rs[r + 1];
  float a0 = 0.f, a1 = 0.f, a2 = 0.f, a3 = 0.f;
  int e = e0;
  for (; e + 3 < e1; e += 4) {
    a0 += sval[e]     * t2[(size_t)scol[e] * NCLS + f];
    a1 += sval[e + 1] * t2[(size_t)scol[e + 1] * NCLS + f];
    a2 += sval[e + 2] * t2[(size_t)scol[e + 2] * NCLS + f];
    a3 += sval[e + 3] * t2[(size_t)scol[e + 3] * NCLS + f];
  }
  for (; e < e1; ++e)
    a0 += sval[e] * t2[(size_t)scol[e] * NCLS + f];
  out[(size_t)r * NCLS + f] = (a0 + a1) + (a2 + a3) + b2[f];
}

extern "C" void kernel_launch(void* const* d_in, const int* in_sizes, int n_in,
                              void* d_out, int out_size, void* d_ws, size_t ws_size,
                              hipStream_t stream) {
  (void)in_sizes; (void)n_in; (void)out_size; (void)ws_size;
  const int*   x    = (const int*)  d_in[0];
  const int*   rows = (const int*)  d_in[1];
  const int*   cols = (const int*)  d_in[2];
  const float* vals = (const float*)d_in[3];
  const float* emb  = (const float*)d_in[4];
  const float* W1   = (const float*)d_in[5];
  const float* b1   = (const float*)d_in[6];
  const float* W2   = (const float*)d_in[7];
  const float* b2   = (const float*)d_in[8];
  float* out = (float*)d_out;

  char* ws = (char*)d_ws;
  size_t off = 0;
  auto take = [&](size_t bytes) {
    char* p = ws + off;
    off = (off + bytes + 255) & ~(size_t)255;
    return p;
  };
  unsigned short* embr = (unsigned short*)take((size_t)EMBROWS * 128 * 2);
  unsigned short* w1t  = (unsigned short*)take((size_t)NHID * INCH * 2);
  unsigned short* t1s  = (unsigned short*)take((size_t)NNODES * NHID * 2);
  unsigned short* h1   = (unsigned short*)take((size_t)NNODES * NHID * 2);
  float*          t2   = (float*)take((size_t)NNODES * NCLS * 4);
  int*            counts = (int*)take((size_t)2 * NNODES * 4);   // counts + cursor adjacent
  int*            cursor = counts + NNODES;
  int*            rs     = (int*)take((size_t)(NNODES + 1) * 4);
  int*            scol   = (int*)take((size_t)NEDGE * 4);
  int*            scolb  = (int*)take((size_t)NEDGE * 4);
  float*          sval   = (float*)take((size_t)NEDGE * 4);

  hipMemsetAsync(counts, 0, (size_t)2 * NNODES * 4, stream);

  k_embr<<<(EMBROWS * 128 / 4 + 255) / 256, 256, 0, stream>>>(emb, embr);
  k_w1t<<<dim3(INCH / 64, NHID / 64), 256, 0, stream>>>(W1, w1t);
  k_hist<<<(NEDGE + 255) / 256, 256, 0, stream>>>(rows, counts);
  k_scan<<<1, 256, 0, stream>>>(counts, rs);
  k_scatter<<<(NEDGE + 255) / 256, 256, 0, stream>>>(rows, cols, vals, rs, cursor, scol, scolb, sval);
  k_gemm1<<<((NNODES + 127) / 128) * (NHID / 128), 256, 0, stream>>>(x, embr, w1t, t1s);
  k_spmm1<<<((NNODES + 31) / 32) * 8, 256, 0, stream>>>(rs, scolb, sval, t1s, b1, h1);
  k_gemm2<<<(NNODES + 63) / 64, 256, 0, stream>>>(h1, W2, t2);
  k_spmm2<<<(NNODES + 15) / 16, 256, 0, stream>>>(rs, scol, sval, t2, b2, out);
}

// Round 7
// 171.007 us; speedup vs baseline: 1.0879x; 1.0879x over previous
//
#include <hip/hip_runtime.h>

#define NNODES 15279
#define NEDGE  488928
#define INCH   1024
#define NHID   512
#define NCLS   16
#define EMBROWS 10001

#define NB_EMBR 1251   // ceil(10001*128/4 / 256)
#define NB_W1T  128    // 16 k-tiles x 8 n-tiles
#define NB_HIST 1910   // ceil(488928/256)

using short8 = __attribute__((ext_vector_type(8))) short;
using f32x4  = __attribute__((ext_vector_type(4))) float;
using f32x2  = __attribute__((ext_vector_type(2))) float;

__device__ __forceinline__ float bf2f(unsigned short u) {
  union { unsigned int i; float f; } v; v.i = ((unsigned int)u) << 16; return v.f;
}
__device__ __forceinline__ float asf(unsigned int u) {
  union { unsigned int i; float f; } v; v.i = u; return v.f;
}
__device__ __forceinline__ unsigned short f2bf(float f) {
  union { float ff; unsigned int i; } v; v.ff = f;
  return (unsigned short)((v.i + 0x7FFFu + ((v.i >> 16) & 1u)) >> 16);
}

// ---------- prep: relu(emb)->bf16 embr  |  W1 transpose->bf16  |  edge histogram ----------
__global__ __launch_bounds__(256) void k_prep(const float* __restrict__ emb,
                                              unsigned short* __restrict__ embr,
                                              const float* __restrict__ W1,
                                              unsigned short* __restrict__ w1t,
                                              const int* __restrict__ rows,
                                              int* __restrict__ counts) {
  __shared__ float tile[64][65];
  int b = blockIdx.x;
  int t = threadIdx.x;
  if (b < NB_EMBR) {
    int g = b * 256 + t;
    if (g * 4 < EMBROWS * 128) {
      const float4 v = *(const float4*)&emb[g * 4];
      unsigned int lo = (unsigned int)f2bf(fmaxf(v.x, 0.f)) | ((unsigned int)f2bf(fmaxf(v.y, 0.f)) << 16);
      unsigned int hi = (unsigned int)f2bf(fmaxf(v.z, 0.f)) | ((unsigned int)f2bf(fmaxf(v.w, 0.f)) << 16);
      uint2 o; o.x = lo; o.y = hi;
      *(uint2*)&embr[g * 4] = o;
    }
  } else if (b < NB_EMBR + NB_W1T) {
    int b2 = b - NB_EMBR;
    int k0 = (b2 & 15) * 64, n0 = (b2 >> 4) * 64;
    int c = t & 63, r4 = t >> 6;
    for (int i = 0; i < 16; ++i) {
      int r = r4 + i * 4;
      tile[r][c] = W1[(k0 + r) * NHID + n0 + c];
    }
    __syncthreads();
    for (int i = 0; i < 16; ++i) {
      int nr = r4 + i * 4;
      w1t[(size_t)(n0 + nr) * INCH + k0 + c] = f2bf(tile[c][nr]);
    }
  } else {
    int e = (b - NB_EMBR - NB_W1T) * 256 + t;
    if (e < NEDGE) atomicAdd(&counts[rows[e]], 1);
  }
}

__global__ __launch_bounds__(256) void k_scan(const int* __restrict__ counts,
                                              int* __restrict__ rs) {
  int t = threadIdx.x;
  int lo = t * 60, hi = lo + 60;
  if (hi > NNODES) hi = NNODES;
  if (lo > NNODES) lo = NNODES;
  int s = 0;
  for (int i = lo; i < hi; ++i) s += counts[i];
  int lane = t & 63, wid = t >> 6;
  int v = s;
  for (int d = 1; d < 64; d <<= 1) {
    int u = __shfl_up(v, d);
    if (lane >= d) v += u;
  }
  __shared__ int wsum[4];
  if (lane == 63) wsum[wid] = v;
  __syncthreads();
  int wbase = 0;
  for (int w2 = 0; w2 < wid; ++w2) wbase += wsum[w2];
  int run = wbase + v - s;
  for (int i = lo; i < hi; ++i) { rs[i] = run; run += counts[i]; }
  if (t == 255) rs[NNODES] = run;
}

__global__ __launch_bounds__(256) void k_scatter(const int* __restrict__ rows,
                                                 const int* __restrict__ cols,
                                                 const float* __restrict__ vals,
                                                 const int* __restrict__ rs,
                                                 int* __restrict__ cursor,
                                                 int* __restrict__ scol,
                                                 int* __restrict__ scolb,
                                                 float* __restrict__ sval) {
  int e = blockIdx.x * 256 + threadIdx.x;
  if (e < NEDGE) {
    int r = rows[e];
    int p = rs[r] + atomicAdd(&cursor[r], 1);
    int c = cols[e];
    scol[p] = c;
    scolb[p] = c * 128;      // byte offset into a 64-wide bf16 slice row
    sval[p] = vals[e];
  }
}

// ---------- GEMM1: t1s = relu(emb[x]) @ W1, A staged from embr via x-indirection ----------
// s = kt>>1 (embedding slot, constant per K-tile), d = (kt&1)*64 + granule*8.
// Output SLICE-MAJOR t1s[8][NNODES][64].
__global__ __launch_bounds__(256) void k_gemm1(const int* __restrict__ x,
                                               const unsigned short* __restrict__ embr,
                                               const unsigned short* __restrict__ Bt,
                                               unsigned short* __restrict__ Cs) {
  __shared__ unsigned short As[128 * 64];
  __shared__ unsigned short Bs[128 * 64];
  const int t = threadIdx.x;
  const int m0 = (blockIdx.x >> 2) * 128;
  const int n0 = (blockIdx.x & 3) * 128;
  const int w = t >> 6, l = t & 63;
  const int wm = w >> 1, wn = w & 1;
  const int l4 = l >> 4, l15 = l & 15;
  const int rowA = wm * 64 + l15;
  const int colB = wn * 64 + l15;
  f32x4 acc[4][4] = {};

  for (int kt = 0; kt < 16; ++kt) {
    const int k0 = kt * 64;
    const int s = kt >> 1;
    const int dbase = (kt & 1) * 64;
#pragma unroll
    for (int i = 0; i < 4; ++i) {
      int p = i * 256 + t;
      int row = p >> 3, kg = p & 7;
      int skg = (kg ^ (row & 7)) * 8;
      int ga = m0 + row; ga = ga < NNODES ? ga : NNODES - 1;
      int idx = x[ga * 8 + s];
      __builtin_amdgcn_global_load_lds(
          (const __attribute__((address_space(1))) void*)&embr[(size_t)idx * 128 + dbase + skg],
          (__attribute__((address_space(3))) void*)&As[p * 8], 16, 0, 0);
      __builtin_amdgcn_global_load_lds(
          (const __attribute__((address_space(1))) void*)&Bt[(size_t)(n0 + row) * INCH + k0 + skg],
          (__attribute__((address_space(3))) void*)&Bs[p * 8], 16, 0, 0);
    }
    __syncthreads();
    for (int kk = 0; kk < 2; ++kk) {
      short8 af[4], bfr[4];
      for (int m = 0; m < 4; ++m) {
        int r = rowA + m * 16;
        af[m] = *(const short8*)&As[(r * 8 + ((kk * 4 + l4) ^ (r & 7))) * 8];
      }
      for (int n = 0; n < 4; ++n) {
        int c = colB + n * 16;
        bfr[n] = *(const short8*)&Bs[(c * 8 + ((kk * 4 + l4) ^ (c & 7))) * 8];
      }
      for (int m = 0; m < 4; ++m)
        for (int n = 0; n < 4; ++n)
          acc[m][n] = __builtin_amdgcn_mfma_f32_16x16x32_bf16(af[m], bfr[n], acc[m][n], 0, 0, 0);
    }
    __syncthreads();
  }
  const int rb = m0 + wm * 64 + l4 * 4;
  const int cb = n0 + wn * 64 + l15;
  for (int m = 0; m < 4; ++m)
    for (int j = 0; j < 4; ++j) {
      int r = rb + m * 16 + j;
      if (r < NNODES)
        for (int n = 0; n < 4; ++n) {
          int c = cb + n * 16;
          Cs[((size_t)(c >> 6) * NNODES + r) * 64 + (c & 63)] = f2bf(acc[m][n][j]);
        }
    }
}

// ---------- spmm1 + bias + relu, feature-sliced, 4 rows/warp x 2 edge-lanes, unroll x4 ----------
// blockIdx&7 = slice (round-robin XCD dispatch -> slice stays in one 4MB L2).
// lane: rloc=l>>4 (row 0..3), el=(l>>3)&1 (edge lane), ft=l&7 (8 bf16 feats = 16B).
__global__ __launch_bounds__(256) void k_spmm1(const int* __restrict__ rs,
                                               const int* __restrict__ scolb,
                                               const float* __restrict__ sval,
                                               const unsigned short* __restrict__ t1s,
                                               const float* __restrict__ b1,
                                               unsigned short* __restrict__ h1) {
  int b = blockIdx.x;
  int slice = b & 7;
  int rgrp = b >> 3;
  int t = threadIdx.x;
  int wid = t >> 6, lane = t & 63;
  int rloc = lane >> 4, el = (lane >> 3) & 1, ft = lane & 7;
  int r = rgrp * 16 + wid * 4 + rloc;
  bool valid = r < NNODES;
  int rr = valid ? r : NNODES - 1;
  const char* tbase = (const char*)(t1s + (size_t)slice * NNODES * 64) + ft * 16;
  int fglob = slice * 64 + ft * 8;
  int e0 = rs[rr];
  int e1 = valid ? rs[rr + 1] : e0;
  f32x2 acc[4] = {};
  int e = e0 + el;
  for (; e + 6 < e1; e += 8) {
    int c0 = scolb[e], c1 = scolb[e + 2], c2 = scolb[e + 4], c3 = scolb[e + 6];
    float v0 = sval[e], v1 = sval[e + 2], v2 = sval[e + 4], v3 = sval[e + 6];
    uint4 q0 = *(const uint4*)(tbase + (size_t)(unsigned)c0);
    uint4 q1 = *(const uint4*)(tbase + (size_t)(unsigned)c1);
    uint4 q2 = *(const uint4*)(tbase + (size_t)(unsigned)c2);
    uint4 q3 = *(const uint4*)(tbase + (size_t)(unsigned)c3);
    f32x2 w0 = {v0, v0}, w1 = {v1, v1}, w2 = {v2, v2}, w3 = {v3, v3};
    unsigned int u0[4] = {q0.x, q0.y, q0.z, q0.w};
    unsigned int u1[4] = {q1.x, q1.y, q1.z, q1.w};
    unsigned int u2[4] = {q2.x, q2.y, q2.z, q2.w};
    unsigned int u3[4] = {q3.x, q3.y, q3.z, q3.w};
#pragma unroll
    for (int d = 0; d < 4; ++d) {
      f32x2 p0 = {asf(u0[d] << 16), asf(u0[d] & 0xffff0000u)};
      f32x2 p1 = {asf(u1[d] << 16), asf(u1[d] & 0xffff0000u)};
      f32x2 p2 = {asf(u2[d] << 16), asf(u2[d] & 0xffff0000u)};
      f32x2 p3 = {asf(u3[d] << 16), asf(u3[d] & 0xffff0000u)};
      acc[d] += w0 * p0;
      acc[d] += w1 * p1;
      acc[d] += w2 * p2;
      acc[d] += w3 * p3;
    }
  }
  for (; e < e1; e += 2) {
    int c = scolb[e];
    float v = sval[e];
    uint4 a = *(const uint4*)(tbase + (size_t)(unsigned)c);
    f32x2 v2 = {v, v};
    unsigned int ua[4] = {a.x, a.y, a.z, a.w};
#pragma unroll
    for (int d = 0; d < 4; ++d) {
      f32x2 p = {asf(ua[d] << 16), asf(ua[d] & 0xffff0000u)};
      acc[d] += v2 * p;
    }
  }
  // reduce across the 2 edge-lanes (lane bit 3)
#pragma unroll
  for (int d = 0; d < 4; ++d) {
    acc[d].x += __shfl_xor(acc[d].x, 8);
    acc[d].y += __shfl_xor(acc[d].y, 8);
  }
  if (el == 0 && valid) {
    unsigned int o[4];
#pragma unroll
    for (int d = 0; d < 4; ++d) {
      float s0 = fmaxf(acc[d].x + b1[fglob + 2 * d], 0.f);
      float s1 = fmaxf(acc[d].y + b1[fglob + 2 * d + 1], 0.f);
      o[d] = (unsigned int)f2bf(s0) | ((unsigned int)f2bf(s1) << 16);
    }
    uint4 ov; ov.x = o[0]; ov.y = o[1]; ov.z = o[2]; ov.w = o[3];
    *(uint4*)&h1[(size_t)r * NHID + fglob] = ov;
  }
}

// ---------- GEMM2: t2 = h1 @ W2  (MFMA 16x16x32) ----------
__global__ __launch_bounds__(256) void k_gemm2(const unsigned short* __restrict__ h1,
                                               const float* __restrict__ W2,
                                               float* __restrict__ t2) {
  __shared__ unsigned short w2t[16 * 520];
  int t = threadIdx.x;
#pragma unroll
  for (int i = 0; i < 32; ++i) {
    int p = i * 256 + t;
    int k = p >> 4, f = p & 15;
    w2t[f * 520 + k] = f2bf(W2[p]);
  }
  __syncthreads();
  int w = t >> 6, l = t & 63;
  int l15 = l & 15, l4 = l >> 4;
  int r0 = blockIdx.x * 64 + w * 16;
  int row = r0 + l15; row = row < NNODES ? row : NNODES - 1;
  f32x4 acc = {};
#pragma unroll
  for (int kk = 0; kk < 16; ++kk) {
    short8 af = *(const short8*)&h1[(size_t)row * NHID + kk * 32 + l4 * 8];
    short8 bfr = *(const short8*)&w2t[l15 * 520 + kk * 32 + l4 * 8];
    acc = __builtin_amdgcn_mfma_f32_16x16x32_bf16(af, bfr, acc, 0, 0, 0);
  }
#pragma unroll
  for (int j = 0; j < 4; ++j) {
    int r = r0 + l4 * 4 + j;
    if (r < NNODES) t2[(size_t)r * NCLS + l15] = acc[j];
  }
}

// ---------- spmm2 + bias, unroll x4 ----------
__global__ __launch_bounds__(256) void k_spmm2(const int* __restrict__ rs,
                                               const int* __restrict__ scol,
                                               const float* __restrict__ sval,
                                               const float* __restrict__ t2,
                                               const float* __restrict__ b2,
                                               float* __restrict__ out) {
  int t = threadIdx.x;
  int f = t & 15, rl = t >> 4;
  int r = blockIdx.x * 16 + rl;
  if (r >= NNODES) return;
  int e0 = rs[r], e1 = rs[r + 1];
  float a0 = 0.f, a1 = 0.f, a2 = 0.f, a3 = 0.f;
  int e = e0;
  for (; e + 3 < e1; e += 4) {
    a0 += sval[e]     * t2[(size_t)scol[e] * NCLS + f];
    a1 += sval[e + 1] * t2[(size_t)scol[e + 1] * NCLS + f];
    a2 += sval[e + 2] * t2[(size_t)scol[e + 2] * NCLS + f];
    a3 += sval[e + 3] * t2[(size_t)scol[e + 3] * NCLS + f];
  }
  for (; e < e1; ++e)
    a0 += sval[e] * t2[(size_t)scol[e] * NCLS + f];
  out[(size_t)r * NCLS + f] = (a0 + a1) + (a2 + a3) + b2[f];
}

extern "C" void kernel_launch(void* const* d_in, const int* in_sizes, int n_in,
                              void* d_out, int out_size, void* d_ws, size_t ws_size,
                              hipStream_t stream) {
  (void)in_sizes; (void)n_in; (void)out_size; (void)ws_size;
  const int*   x    = (const int*)  d_in[0];
  const int*   rows = (const int*)  d_in[1];
  const int*   cols = (const int*)  d_in[2];
  const float* vals = (const float*)d_in[3];
  const float* emb  = (const float*)d_in[4];
  const float* W1   = (const float*)d_in[5];
  const float* b1   = (const float*)d_in[6];
  const float* W2   = (const float*)d_in[7];
  const float* b2   = (const float*)d_in[8];
  float* out = (float*)d_out;

  char* ws = (char*)d_ws;
  size_t off = 0;
  auto take = [&](size_t bytes) {
    char* p = ws + off;
    off = (off + bytes + 255) & ~(size_t)255;
    return p;
  };
  unsigned short* embr = (unsigned short*)take((size_t)EMBROWS * 128 * 2);
  unsigned short* w1t  = (unsigned short*)take((size_t)NHID * INCH * 2);
  unsigned short* t1s  = (unsigned short*)take((size_t)NNODES * NHID * 2);
  unsigned short* h1   = (unsigned short*)take((size_t)NNODES * NHID * 2);
  float*          t2   = (float*)take((size_t)NNODES * NCLS * 4);
  int*            counts = (int*)take((size_t)2 * NNODES * 4);   // counts + cursor adjacent
  int*            cursor = counts + NNODES;
  int*            rs     = (int*)take((size_t)(NNODES + 1) * 4);
  int*            scol   = (int*)take((size_t)NEDGE * 4);
  int*            scolb  = (int*)take((size_t)NEDGE * 4);
  float*          sval   = (float*)take((size_t)NEDGE * 4);

  hipMemsetAsync(counts, 0, (size_t)2 * NNODES * 4, stream);

  k_prep<<<NB_EMBR + NB_W1T + NB_HIST, 256, 0, stream>>>(emb, embr, W1, w1t, rows, counts);
  k_scan<<<1, 256, 0, stream>>>(counts, rs);
  k_scatter<<<(NEDGE + 255) / 256, 256, 0, stream>>>(rows, cols, vals, rs, cursor, scol, scolb, sval);
  k_gemm1<<<((NNODES + 127) / 128) * (NHID / 128), 256, 0, stream>>>(x, embr, w1t, t1s);
  k_spmm1<<<((NNODES + 15) / 16) * 8, 256, 0, stream>>>(rs, scolb, sval, t1s, b1, h1);
  k_gemm2<<<(NNODES + 63) / 64, 256, 0, stream>>>(h1, W2, t2);
  k_spmm2<<<(NNODES + 15) / 16, 256, 0, stream>>>(rs, scol, sval, t2, b2, out);
}

// Round 8
// 163.228 us; speedup vs baseline: 1.1397x; 1.0477x over previous
//
#include <hip/hip_runtime.h>

#define NNODES 15279
#define NEDGE  488928
#define INCH   1024
#define NHID   512
#define NCLS   16
#define EMBROWS 10001

#define NB_EMBR 1251   // ceil(10001*128/4 / 256)
#define NB_W1T  128    // 16 k-tiles x 8 n-tiles
#define NB_HIST 1910   // ceil(488928/256)

using short8 = __attribute__((ext_vector_type(8))) short;
using f32x4  = __attribute__((ext_vector_type(4))) float;
using f32x2  = __attribute__((ext_vector_type(2))) float;

__device__ __forceinline__ float bf2f(unsigned short u) {
  union { unsigned int i; float f; } v; v.i = ((unsigned int)u) << 16; return v.f;
}
__device__ __forceinline__ float asf(unsigned int u) {
  union { unsigned int i; float f; } v; v.i = u; return v.f;
}
__device__ __forceinline__ unsigned short f2bf(float f) {
  union { float ff; unsigned int i; } v; v.ff = f;
  return (unsigned short)((v.i + 0x7FFFu + ((v.i >> 16) & 1u)) >> 16);
}

// ---------- prep: relu(emb)->bf16 embr  |  W1 transpose->bf16  |  edge histogram ----------
__global__ __launch_bounds__(256) void k_prep(const float* __restrict__ emb,
                                              unsigned short* __restrict__ embr,
                                              const float* __restrict__ W1,
                                              unsigned short* __restrict__ w1t,
                                              const int* __restrict__ rows,
                                              int* __restrict__ counts) {
  __shared__ float tile[64][65];
  int b = blockIdx.x;
  int t = threadIdx.x;
  if (b < NB_EMBR) {
    int g = b * 256 + t;
    if (g * 4 < EMBROWS * 128) {
      const float4 v = *(const float4*)&emb[g * 4];
      unsigned int lo = (unsigned int)f2bf(fmaxf(v.x, 0.f)) | ((unsigned int)f2bf(fmaxf(v.y, 0.f)) << 16);
      unsigned int hi = (unsigned int)f2bf(fmaxf(v.z, 0.f)) | ((unsigned int)f2bf(fmaxf(v.w, 0.f)) << 16);
      uint2 o; o.x = lo; o.y = hi;
      *(uint2*)&embr[g * 4] = o;
    }
  } else if (b < NB_EMBR + NB_W1T) {
    int b2 = b - NB_EMBR;
    int k0 = (b2 & 15) * 64, n0 = (b2 >> 4) * 64;
    int c = t & 63, r4 = t >> 6;
    for (int i = 0; i < 16; ++i) {
      int r = r4 + i * 4;
      tile[r][c] = W1[(k0 + r) * NHID + n0 + c];
    }
    __syncthreads();
    for (int i = 0; i < 16; ++i) {
      int nr = r4 + i * 4;
      w1t[(size_t)(n0 + nr) * INCH + k0 + c] = f2bf(tile[c][nr]);
    }
  } else {
    int e = (b - NB_EMBR - NB_W1T) * 256 + t;
    if (e < NEDGE) atomicAdd(&counts[rows[e]], 1);
  }
}

__global__ __launch_bounds__(256) void k_scan(const int* __restrict__ counts,
                                              int* __restrict__ rs) {
  int t = threadIdx.x;
  int lo = t * 60, hi = lo + 60;
  if (hi > NNODES) hi = NNODES;
  if (lo > NNODES) lo = NNODES;
  int s = 0;
  for (int i = lo; i < hi; ++i) s += counts[i];
  int lane = t & 63, wid = t >> 6;
  int v = s;
  for (int d = 1; d < 64; d <<= 1) {
    int u = __shfl_up(v, d);
    if (lane >= d) v += u;
  }
  __shared__ int wsum[4];
  if (lane == 63) wsum[wid] = v;
  __syncthreads();
  int wbase = 0;
  for (int w2 = 0; w2 < wid; ++w2) wbase += wsum[w2];
  int run = wbase + v - s;
  for (int i = lo; i < hi; ++i) { rs[i] = run; run += counts[i]; }
  if (t == 255) rs[NNODES] = run;
}

__global__ __launch_bounds__(256) void k_scatter(const int* __restrict__ rows,
                                                 const int* __restrict__ cols,
                                                 const float* __restrict__ vals,
                                                 const int* __restrict__ rs,
                                                 int* __restrict__ cursor,
                                                 int* __restrict__ scol,
                                                 int* __restrict__ scolb,
                                                 float* __restrict__ sval) {
  int e = blockIdx.x * 256 + threadIdx.x;
  if (e < NEDGE) {
    int r = rows[e];
    int p = rs[r] + atomicAdd(&cursor[r], 1);
    int c = cols[e];
    scol[p] = c;
    scolb[p] = c * 128;      // byte offset into a 64-wide bf16 slice row
    sval[p] = vals[e];
  }
}

// ---------- GEMM1: t1s = relu(emb[x]) @ W1 ----------
// BM=128 BN=64, grid = 120 m-tiles x 8 n-tiles = 960 blocks (~3.75/CU).
// A staged from embr (2.6MB, L2-resident) via x-indirection; per-thread row
// indices preloaded to REGISTERS (statically indexed via full kt unroll) so
// the stage path has no dependent L2 load. blockIdx&7 = n-tile = output slice.
__global__ __launch_bounds__(256) void k_gemm1(const int* __restrict__ x,
                                               const unsigned short* __restrict__ embr,
                                               const unsigned short* __restrict__ Bt,
                                               unsigned short* __restrict__ Cs) {
  __shared__ unsigned short As[128 * 64];
  __shared__ unsigned short Bs[64 * 64];
  const int t = threadIdx.x;
  const int m0 = (blockIdx.x >> 3) * 128;
  const int n0 = (blockIdx.x & 7) * 64;
  const int w = t >> 6, l = t & 63;
  const int wm = w >> 1, wn = w & 1;
  const int l4 = l >> 4, l15 = l & 15;
  const int rowA = wm * 64 + l15;
  const int colB = wn * 32 + l15;
  f32x4 acc[4][2] = {};

  // preload this thread's 4 staging-row x-indices (8 slots each) into regs
  int xidx[4][8];
#pragma unroll
  for (int i = 0; i < 4; ++i) {
    int grow = m0 + (t >> 3) + i * 32;
    grow = grow < NNODES ? grow : NNODES - 1;
    *(int4*)&xidx[i][0] = *(const int4*)&x[grow * 8];
    *(int4*)&xidx[i][4] = *(const int4*)&x[grow * 8 + 4];
  }

#pragma unroll
  for (int kt = 0; kt < 16; ++kt) {
    const int k0 = kt * 64;
    const int s = kt >> 1;
    const int dbase = (kt & 1) * 64;
#pragma unroll
    for (int i = 0; i < 4; ++i) {
      int p = i * 256 + t;
      int row = i * 32 + (t >> 3);
      int skg = ((t & 7) ^ (row & 7)) * 8;
      __builtin_amdgcn_global_load_lds(
          (const __attribute__((address_space(1))) void*)&embr[(size_t)xidx[i][s] * 128 + dbase + skg],
          (__attribute__((address_space(3))) void*)&As[p * 8], 16, 0, 0);
    }
#pragma unroll
    for (int i = 0; i < 2; ++i) {
      int p = i * 256 + t;
      int row = i * 32 + (t >> 3);
      int skg = ((t & 7) ^ (row & 7)) * 8;
      __builtin_amdgcn_global_load_lds(
          (const __attribute__((address_space(1))) void*)&Bt[(size_t)(n0 + row) * INCH + k0 + skg],
          (__attribute__((address_space(3))) void*)&Bs[p * 8], 16, 0, 0);
    }
    __syncthreads();
#pragma unroll
    for (int kk = 0; kk < 2; ++kk) {
      short8 af[4], bfr[2];
#pragma unroll
      for (int m = 0; m < 4; ++m) {
        int r = rowA + m * 16;
        af[m] = *(const short8*)&As[(r * 8 + ((kk * 4 + l4) ^ (r & 7))) * 8];
      }
#pragma unroll
      for (int n = 0; n < 2; ++n) {
        int c = colB + n * 16;
        bfr[n] = *(const short8*)&Bs[(c * 8 + ((kk * 4 + l4) ^ (c & 7))) * 8];
      }
#pragma unroll
      for (int m = 0; m < 4; ++m)
#pragma unroll
        for (int n = 0; n < 2; ++n)
          acc[m][n] = __builtin_amdgcn_mfma_f32_16x16x32_bf16(af[m], bfr[n], acc[m][n], 0, 0, 0);
    }
    __syncthreads();
  }
  const int rb = m0 + wm * 64 + l4 * 4;
  const int cb = wn * 32 + l15;           // column within the 64-wide slice
  unsigned short* Cb = Cs + (size_t)(n0 >> 6) * NNODES * 64;
#pragma unroll
  for (int m = 0; m < 4; ++m)
#pragma unroll
    for (int j = 0; j < 4; ++j) {
      int r = rb + m * 16 + j;
      if (r < NNODES) {
        Cb[(size_t)r * 64 + cb]      = f2bf(acc[m][0][j]);
        Cb[(size_t)r * 64 + cb + 16] = f2bf(acc[m][1][j]);
      }
    }
}

// ---------- spmm1 + bias + relu, feature-sliced, 4 rows/warp x 2 edge-lanes, unroll x4 ----------
__global__ __launch_bounds__(256) void k_spmm1(const int* __restrict__ rs,
                                               const int* __restrict__ scolb,
                                               const float* __restrict__ sval,
                                               const unsigned short* __restrict__ t1s,
                                               const float* __restrict__ b1,
                                               unsigned short* __restrict__ h1) {
  int b = blockIdx.x;
  int slice = b & 7;
  int rgrp = b >> 3;
  int t = threadIdx.x;
  int wid = t >> 6, lane = t & 63;
  int rloc = lane >> 4, el = (lane >> 3) & 1, ft = lane & 7;
  int r = rgrp * 16 + wid * 4 + rloc;
  bool valid = r < NNODES;
  int rr = valid ? r : NNODES - 1;
  const char* tbase = (const char*)(t1s + (size_t)slice * NNODES * 64) + ft * 16;
  int fglob = slice * 64 + ft * 8;
  int e0 = rs[rr];
  int e1 = valid ? rs[rr + 1] : e0;
  f32x2 acc[4] = {};
  int e = e0 + el;
  for (; e + 6 < e1; e += 8) {
    int c0 = scolb[e], c1 = scolb[e + 2], c2 = scolb[e + 4], c3 = scolb[e + 6];
    float v0 = sval[e], v1 = sval[e + 2], v2 = sval[e + 4], v3 = sval[e + 6];
    uint4 q0 = *(const uint4*)(tbase + (size_t)(unsigned)c0);
    uint4 q1 = *(const uint4*)(tbase + (size_t)(unsigned)c1);
    uint4 q2 = *(const uint4*)(tbase + (size_t)(unsigned)c2);
    uint4 q3 = *(const uint4*)(tbase + (size_t)(unsigned)c3);
    f32x2 w0 = {v0, v0}, w1 = {v1, v1}, w2 = {v2, v2}, w3 = {v3, v3};
    unsigned int u0[4] = {q0.x, q0.y, q0.z, q0.w};
    unsigned int u1[4] = {q1.x, q1.y, q1.z, q1.w};
    unsigned int u2[4] = {q2.x, q2.y, q2.z, q2.w};
    unsigned int u3[4] = {q3.x, q3.y, q3.z, q3.w};
#pragma unroll
    for (int d = 0; d < 4; ++d) {
      f32x2 p0 = {asf(u0[d] << 16), asf(u0[d] & 0xffff0000u)};
      f32x2 p1 = {asf(u1[d] << 16), asf(u1[d] & 0xffff0000u)};
      f32x2 p2 = {asf(u2[d] << 16), asf(u2[d] & 0xffff0000u)};
      f32x2 p3 = {asf(u3[d] << 16), asf(u3[d] & 0xffff0000u)};
      acc[d] += w0 * p0;
      acc[d] += w1 * p1;
      acc[d] += w2 * p2;
      acc[d] += w3 * p3;
    }
  }
  for (; e < e1; e += 2) {
    int c = scolb[e];
    float v = sval[e];
    uint4 a = *(const uint4*)(tbase + (size_t)(unsigned)c);
    f32x2 v2 = {v, v};
    unsigned int ua[4] = {a.x, a.y, a.z, a.w};
#pragma unroll
    for (int d = 0; d < 4; ++d) {
      f32x2 p = {asf(ua[d] << 16), asf(ua[d] & 0xffff0000u)};
      acc[d] += v2 * p;
    }
  }
#pragma unroll
  for (int d = 0; d < 4; ++d) {
    acc[d].x += __shfl_xor(acc[d].x, 8);
    acc[d].y += __shfl_xor(acc[d].y, 8);
  }
  if (el == 0 && valid) {
    unsigned int o[4];
#pragma unroll
    for (int d = 0; d < 4; ++d) {
      float s0 = fmaxf(acc[d].x + b1[fglob + 2 * d], 0.f);
      float s1 = fmaxf(acc[d].y + b1[fglob + 2 * d + 1], 0.f);
      o[d] = (unsigned int)f2bf(s0) | ((unsigned int)f2bf(s1) << 16);
    }
    uint4 ov; ov.x = o[0]; ov.y = o[1]; ov.z = o[2]; ov.w = o[3];
    *(uint4*)&h1[(size_t)r * NHID + fglob] = ov;
  }
}

// ---------- GEMM2: t2 = h1 @ W2  (MFMA 16x16x32) ----------
__global__ __launch_bounds__(256) void k_gemm2(const unsigned short* __restrict__ h1,
                                               const float* __restrict__ W2,
                                               float* __restrict__ t2) {
  __shared__ unsigned short w2t[16 * 520];
  int t = threadIdx.x;
#pragma unroll
  for (int i = 0; i < 32; ++i) {
    int p = i * 256 + t;
    int k = p >> 4, f = p & 15;
    w2t[f * 520 + k] = f2bf(W2[p]);
  }
  __syncthreads();
  int w = t >> 6, l = t & 63;
  int l15 = l & 15, l4 = l >> 4;
  int r0 = blockIdx.x * 64 + w * 16;
  int row = r0 + l15; row = row < NNODES ? row : NNODES - 1;
  f32x4 acc = {};
#pragma unroll
  for (int kk = 0; kk < 16; ++kk) {
    short8 af = *(const short8*)&h1[(size_t)row * NHID + kk * 32 + l4 * 8];
    short8 bfr = *(const short8*)&w2t[l15 * 520 + kk * 32 + l4 * 8];
    acc = __builtin_amdgcn_mfma_f32_16x16x32_bf16(af, bfr, acc, 0, 0, 0);
  }
#pragma unroll
  for (int j = 0; j < 4; ++j) {
    int r = r0 + l4 * 4 + j;
    if (r < NNODES) t2[(size_t)r * NCLS + l15] = acc[j];
  }
}

// ---------- spmm2 + bias, unroll x4 ----------
__global__ __launch_bounds__(256) void k_spmm2(const int* __restrict__ rs,
                                               const int* __restrict__ scol,
                                               const float* __restrict__ sval,
                                               const float* __restrict__ t2,
                                               const float* __restrict__ b2,
                                               float* __restrict__ out) {
  int t = threadIdx.x;
  int f = t & 15, rl = t >> 4;
  int r = blockIdx.x * 16 + rl;
  if (r >= NNODES) return;
  int e0 = rs[r], e1 = rs[r + 1];
  float a0 = 0.f, a1 = 0.f, a2 = 0.f, a3 = 0.f;
  int e = e0;
  for (; e + 3 < e1; e += 4) {
    a0 += sval[e]     * t2[(size_t)scol[e] * NCLS + f];
    a1 += sval[e + 1] * t2[(size_t)scol[e + 1] * NCLS + f];
    a2 += sval[e + 2] * t2[(size_t)scol[e + 2] * NCLS + f];
    a3 += sval[e + 3] * t2[(size_t)scol[e + 3] * NCLS + f];
  }
  for (; e < e1; ++e)
    a0 += sval[e] * t2[(size_t)scol[e] * NCLS + f];
  out[(size_t)r * NCLS + f] = (a0 + a1) + (a2 + a3) + b2[f];
}

extern "C" void kernel_launch(void* const* d_in, const int* in_sizes, int n_in,
                              void* d_out, int out_size, void* d_ws, size_t ws_size,
                              hipStream_t stream) {
  (void)in_sizes; (void)n_in; (void)out_size; (void)ws_size;
  const int*   x    = (const int*)  d_in[0];
  const int*   rows = (const int*)  d_in[1];
  const int*   cols = (const int*)  d_in[2];
  const float* vals = (const float*)d_in[3];
  const float* emb  = (const float*)d_in[4];
  const float* W1   = (const float*)d_in[5];
  const float* b1   = (const float*)d_in[6];
  const float* W2   = (const float*)d_in[7];
  const float* b2   = (const float*)d_in[8];
  float* out = (float*)d_out;

  char* ws = (char*)d_ws;
  size_t off = 0;
  auto take = [&](size_t bytes) {
    char* p = ws + off;
    off = (off + bytes + 255) & ~(size_t)255;
    return p;
  };
  unsigned short* embr = (unsigned short*)take((size_t)EMBROWS * 128 * 2);
  unsigned short* w1t  = (unsigned short*)take((size_t)NHID * INCH * 2);
  unsigned short* t1s  = (unsigned short*)take((size_t)NNODES * NHID * 2);
  unsigned short* h1   = (unsigned short*)take((size_t)NNODES * NHID * 2);
  float*          t2   = (float*)take((size_t)NNODES * NCLS * 4);
  int*            counts = (int*)take((size_t)2 * NNODES * 4);   // counts + cursor adjacent
  int*            cursor = counts + NNODES;
  int*            rs     = (int*)take((size_t)(NNODES + 1) * 4);
  int*            scol   = (int*)take((size_t)NEDGE * 4);
  int*            scolb  = (int*)take((size_t)NEDGE * 4);
  float*          sval   = (float*)take((size_t)NEDGE * 4);

  hipMemsetAsync(counts, 0, (size_t)2 * NNODES * 4, stream);

  k_prep<<<NB_EMBR + NB_W1T + NB_HIST, 256, 0, stream>>>(emb, embr, W1, w1t, rows, counts);
  k_scan<<<1, 256, 0, stream>>>(counts, rs);
  k_scatter<<<(NEDGE + 255) / 256, 256, 0, stream>>>(rows, cols, vals, rs, cursor, scol, scolb, sval);
  k_gemm1<<<((NNODES + 127) / 128) * 8, 256, 0, stream>>>(x, embr, w1t, t1s);
  k_spmm1<<<((NNODES + 15) / 16) * 8, 256, 0, stream>>>(rs, scolb, sval, t1s, b1, h1);
  k_gemm2<<<(NNODES + 63) / 64, 256, 0, stream>>>(h1, W2, t2);
  k_spmm2<<<(NNODES + 15) / 16, 256, 0, stream>>>(rs, scol, sval, t2, b2, out);
}

// Round 9
// 155.106 us; speedup vs baseline: 1.1994x; 1.0524x over previous
//
#include <hip/hip_runtime.h>

#define NNODES 15279
#define NEDGE  488928
#define INCH   1024
#define NHID   512
#define NCLS   16
#define EMBROWS 10001

#define NB_EMBR 1251   // ceil(10001*128/4 / 256)
#define NB_W1T  128    // 16 k-tiles x 8 n-tiles
#define NB_HIST 1910   // ceil(488928/256)

using short8 = __attribute__((ext_vector_type(8))) short;
using f32x4  = __attribute__((ext_vector_type(4))) float;
using f32x2  = __attribute__((ext_vector_type(2))) float;

__device__ __forceinline__ float bf2f(unsigned short u) {
  union { unsigned int i; float f; } v; v.i = ((unsigned int)u) << 16; return v.f;
}
__device__ __forceinline__ float asf(unsigned int u) {
  union { unsigned int i; float f; } v; v.i = u; return v.f;
}
__device__ __forceinline__ unsigned short f2bf(float f) {
  union { float ff; unsigned int i; } v; v.ff = f;
  return (unsigned short)((v.i + 0x7FFFu + ((v.i >> 16) & 1u)) >> 16);
}

// ---------- prep: relu(emb)->bf16 embr  |  W1 transpose->bf16  |  edge histogram ----------
__global__ __launch_bounds__(256) void k_prep(const float* __restrict__ emb,
                                              unsigned short* __restrict__ embr,
                                              const float* __restrict__ W1,
                                              unsigned short* __restrict__ w1t,
                                              const int* __restrict__ rows,
                                              int* __restrict__ counts) {
  __shared__ float tile[64][65];
  int b = blockIdx.x;
  int t = threadIdx.x;
  if (b < NB_EMBR) {
    int g = b * 256 + t;
    if (g * 4 < EMBROWS * 128) {
      const float4 v = *(const float4*)&emb[g * 4];
      unsigned int lo = (unsigned int)f2bf(fmaxf(v.x, 0.f)) | ((unsigned int)f2bf(fmaxf(v.y, 0.f)) << 16);
      unsigned int hi = (unsigned int)f2bf(fmaxf(v.z, 0.f)) | ((unsigned int)f2bf(fmaxf(v.w, 0.f)) << 16);
      uint2 o; o.x = lo; o.y = hi;
      *(uint2*)&embr[g * 4] = o;
    }
  } else if (b < NB_EMBR + NB_W1T) {
    int b2 = b - NB_EMBR;
    int k0 = (b2 & 15) * 64, n0 = (b2 >> 4) * 64;
    int c = t & 63, r4 = t >> 6;
    for (int i = 0; i < 16; ++i) {
      int r = r4 + i * 4;
      tile[r][c] = W1[(k0 + r) * NHID + n0 + c];
    }
    __syncthreads();
    for (int i = 0; i < 16; ++i) {
      int nr = r4 + i * 4;
      w1t[(size_t)(n0 + nr) * INCH + k0 + c] = f2bf(tile[c][nr]);
    }
  } else {
    int e = (b - NB_EMBR - NB_W1T) * 256 + t;
    if (e < NEDGE) atomicAdd(&counts[rows[e]], 1);
  }
}

// ---------- exclusive scan, 1024 threads x 15 elems ----------
__global__ __launch_bounds__(1024) void k_scan(const int* __restrict__ counts,
                                               int* __restrict__ rs) {
  int t = threadIdx.x;
  int lo = t * 15, hi = lo + 15;
  if (hi > NNODES) hi = NNODES;
  if (lo > NNODES) lo = NNODES;
  int s = 0;
  for (int i = lo; i < hi; ++i) s += counts[i];
  int lane = t & 63, wid = t >> 6;
  int v = s;
  for (int d = 1; d < 64; d <<= 1) {
    int u = __shfl_up(v, d);
    if (lane >= d) v += u;
  }
  __shared__ int wsum[16];
  if (lane == 63) wsum[wid] = v;
  __syncthreads();
  int wbase = 0;
  for (int w2 = 0; w2 < wid; ++w2) wbase += wsum[w2];
  int run = wbase + v - s;
  for (int i = lo; i < hi; ++i) { rs[i] = run; run += counts[i]; }
  if (t == 1023) rs[NNODES] = run;
}

// ---------- scatter: CSR with packed edge record (col byte-offset, val) ----------
__global__ __launch_bounds__(256) void k_scatter(const int* __restrict__ rows,
                                                 const int* __restrict__ cols,
                                                 const float* __restrict__ vals,
                                                 const int* __restrict__ rs,
                                                 int* __restrict__ cursor,
                                                 int2* __restrict__ evec) {
  int e = blockIdx.x * 256 + threadIdx.x;
  if (e < NEDGE) {
    int r = rows[e];
    int p = rs[r] + atomicAdd(&cursor[r], 1);
    int2 ev; ev.x = cols[e] * 128; ev.y = __float_as_int(vals[e]);
    evec[p] = ev;
  }
}

// ---------- GEMM1: t1s = relu(emb[x]) @ W1 ----------
// BM=128 BN=64, grid = 120 m-tiles x 8 n-tiles = 960 blocks (~3.75/CU).
// A staged from embr (2.6MB, L2-resident) via x-indirection; per-thread row
// indices preloaded to REGISTERS (statically indexed via full kt unroll).
// blockIdx&7 = n-tile = output slice. Output SLICE-MAJOR t1s[8][NNODES][64].
__global__ __launch_bounds__(256) void k_gemm1(const int* __restrict__ x,
                                               const unsigned short* __restrict__ embr,
                                               const unsigned short* __restrict__ Bt,
                                               unsigned short* __restrict__ Cs) {
  __shared__ unsigned short As[128 * 64];
  __shared__ unsigned short Bs[64 * 64];
  const int t = threadIdx.x;
  const int m0 = (blockIdx.x >> 3) * 128;
  const int n0 = (blockIdx.x & 7) * 64;
  const int w = t >> 6, l = t & 63;
  const int wm = w >> 1, wn = w & 1;
  const int l4 = l >> 4, l15 = l & 15;
  const int rowA = wm * 64 + l15;
  const int colB = wn * 32 + l15;
  f32x4 acc[4][2] = {};

  int xidx[4][8];
#pragma unroll
  for (int i = 0; i < 4; ++i) {
    int grow = m0 + (t >> 3) + i * 32;
    grow = grow < NNODES ? grow : NNODES - 1;
    *(int4*)&xidx[i][0] = *(const int4*)&x[grow * 8];
    *(int4*)&xidx[i][4] = *(const int4*)&x[grow * 8 + 4];
  }

#pragma unroll
  for (int kt = 0; kt < 16; ++kt) {
    const int k0 = kt * 64;
    const int s = kt >> 1;
    const int dbase = (kt & 1) * 64;
#pragma unroll
    for (int i = 0; i < 4; ++i) {
      int p = i * 256 + t;
      int row = i * 32 + (t >> 3);
      int skg = ((t & 7) ^ (row & 7)) * 8;
      __builtin_amdgcn_global_load_lds(
          (const __attribute__((address_space(1))) void*)&embr[(size_t)xidx[i][s] * 128 + dbase + skg],
          (__attribute__((address_space(3))) void*)&As[p * 8], 16, 0, 0);
    }
#pragma unroll
    for (int i = 0; i < 2; ++i) {
      int p = i * 256 + t;
      int row = i * 32 + (t >> 3);
      int skg = ((t & 7) ^ (row & 7)) * 8;
      __builtin_amdgcn_global_load_lds(
          (const __attribute__((address_space(1))) void*)&Bt[(size_t)(n0 + row) * INCH + k0 + skg],
          (__attribute__((address_space(3))) void*)&Bs[p * 8], 16, 0, 0);
    }
    __syncthreads();
#pragma unroll
    for (int kk = 0; kk < 2; ++kk) {
      short8 af[4], bfr[2];
#pragma unroll
      for (int m = 0; m < 4; ++m) {
        int r = rowA + m * 16;
        af[m] = *(const short8*)&As[(r * 8 + ((kk * 4 + l4) ^ (r & 7))) * 8];
      }
#pragma unroll
      for (int n = 0; n < 2; ++n) {
        int c = colB + n * 16;
        bfr[n] = *(const short8*)&Bs[(c * 8 + ((kk * 4 + l4) ^ (c & 7))) * 8];
      }
#pragma unroll
      for (int m = 0; m < 4; ++m)
#pragma unroll
        for (int n = 0; n < 2; ++n)
          acc[m][n] = __builtin_amdgcn_mfma_f32_16x16x32_bf16(af[m], bfr[n], acc[m][n], 0, 0, 0);
    }
    __syncthreads();
  }
  const int rb = m0 + wm * 64 + l4 * 4;
  const int cb = wn * 32 + l15;
  unsigned short* Cb = Cs + (size_t)(n0 >> 6) * NNODES * 64;
#pragma unroll
  for (int m = 0; m < 4; ++m)
#pragma unroll
    for (int j = 0; j < 4; ++j) {
      int r = rb + m * 16 + j;
      if (r < NNODES) {
        Cb[(size_t)r * 64 + cb]      = f2bf(acc[m][0][j]);
        Cb[(size_t)r * 64 + cb + 16] = f2bf(acc[m][1][j]);
      }
    }
}

// ---------- spmm1 + bias + relu, feature-sliced, 4 rows/warp x 2 edge-lanes, unroll x4 ----------
// blockIdx&7 = slice (round-robin XCD dispatch -> slice stays in one 4MB L2).
// lane: rloc=l>>4 (row 0..3), el=(l>>3)&1 (edge lane), ft=l&7 (8 bf16 feats = 16B).
// Edge stream = packed int2 (col byte-offset, val): one dwordx2 per edge.
__global__ __launch_bounds__(256) void k_spmm1(const int* __restrict__ rs,
                                               const int2* __restrict__ evec,
                                               const unsigned short* __restrict__ t1s,
                                               const float* __restrict__ b1,
                                               unsigned short* __restrict__ h1) {
  int b = blockIdx.x;
  int slice = b & 7;
  int rgrp = b >> 3;
  int t = threadIdx.x;
  int wid = t >> 6, lane = t & 63;
  int rloc = lane >> 4, el = (lane >> 3) & 1, ft = lane & 7;
  int r = rgrp * 16 + wid * 4 + rloc;
  bool valid = r < NNODES;
  int rr = valid ? r : NNODES - 1;
  const char* tbase = (const char*)(t1s + (size_t)slice * NNODES * 64) + ft * 16;
  int fglob = slice * 64 + ft * 8;
  int e0 = rs[rr];
  int e1 = valid ? rs[rr + 1] : e0;
  f32x2 acc[4] = {};
  int e = e0 + el;
  for (; e + 6 < e1; e += 8) {
    int2 ev0 = evec[e], ev1 = evec[e + 2], ev2 = evec[e + 4], ev3 = evec[e + 6];
    uint4 q0 = *(const uint4*)(tbase + (size_t)(unsigned)ev0.x);
    uint4 q1 = *(const uint4*)(tbase + (size_t)(unsigned)ev1.x);
    uint4 q2 = *(const uint4*)(tbase + (size_t)(unsigned)ev2.x);
    uint4 q3 = *(const uint4*)(tbase + (size_t)(unsigned)ev3.x);
    float v0 = __int_as_float(ev0.y), v1 = __int_as_float(ev1.y);
    float v2 = __int_as_float(ev2.y), v3 = __int_as_float(ev3.y);
    f32x2 w0 = {v0, v0}, w1 = {v1, v1}, w2 = {v2, v2}, w3 = {v3, v3};
    unsigned int u0[4] = {q0.x, q0.y, q0.z, q0.w};
    unsigned int u1[4] = {q1.x, q1.y, q1.z, q1.w};
    unsigned int u2[4] = {q2.x, q2.y, q2.z, q2.w};
    unsigned int u3[4] = {q3.x, q3.y, q3.z, q3.w};
#pragma unroll
    for (int d = 0; d < 4; ++d) {
      f32x2 p0 = {asf(u0[d] << 16), asf(u0[d] & 0xffff0000u)};
      f32x2 p1 = {asf(u1[d] << 16), asf(u1[d] & 0xffff0000u)};
      f32x2 p2 = {asf(u2[d] << 16), asf(u2[d] & 0xffff0000u)};
      f32x2 p3 = {asf(u3[d] << 16), asf(u3[d] & 0xffff0000u)};
      acc[d] += w0 * p0;
      acc[d] += w1 * p1;
      acc[d] += w2 * p2;
      acc[d] += w3 * p3;
    }
  }
  for (; e < e1; e += 2) {
    int2 ev = evec[e];
    uint4 a = *(const uint4*)(tbase + (size_t)(unsigned)ev.x);
    float v = __int_as_float(ev.y);
    f32x2 v2 = {v, v};
    unsigned int ua[4] = {a.x, a.y, a.z, a.w};
#pragma unroll
    for (int d = 0; d < 4; ++d) {
      f32x2 p = {asf(ua[d] << 16), asf(ua[d] & 0xffff0000u)};
      acc[d] += v2 * p;
    }
  }
#pragma unroll
  for (int d = 0; d < 4; ++d) {
    acc[d].x += __shfl_xor(acc[d].x, 8);
    acc[d].y += __shfl_xor(acc[d].y, 8);
  }
  if (el == 0 && valid) {
    unsigned int o[4];
#pragma unroll
    for (int d = 0; d < 4; ++d) {
      float s0 = fmaxf(acc[d].x + b1[fglob + 2 * d], 0.f);
      float s1 = fmaxf(acc[d].y + b1[fglob + 2 * d + 1], 0.f);
      o[d] = (unsigned int)f2bf(s0) | ((unsigned int)f2bf(s1) << 16);
    }
    uint4 ov; ov.x = o[0]; ov.y = o[1]; ov.z = o[2]; ov.w = o[3];
    *(uint4*)&h1[(size_t)r * NHID + fglob] = ov;
  }
}

// ---------- GEMM2: t2 = h1 @ W2  (MFMA, all 16 A-fragments prefetched) ----------
__global__ __launch_bounds__(256) void k_gemm2(const unsigned short* __restrict__ h1,
                                               const float* __restrict__ W2,
                                               float* __restrict__ t2) {
  __shared__ unsigned short w2t[16 * 520];
  int t = threadIdx.x;
#pragma unroll
  for (int i = 0; i < 32; ++i) {
    int p = i * 256 + t;
    int k = p >> 4, f = p & 15;
    w2t[f * 520 + k] = f2bf(W2[p]);
  }
  int w = t >> 6, l = t & 63;
  int l15 = l & 15, l4 = l >> 4;
  int r0 = blockIdx.x * 64 + w * 16;
  int row = r0 + l15; row = row < NNODES ? row : NNODES - 1;
  // prefetch all 16 A-fragments (independent 16B loads, full MLP)
  short8 af[16];
#pragma unroll
  for (int kk = 0; kk < 16; ++kk)
    af[kk] = *(const short8*)&h1[(size_t)row * NHID + kk * 32 + l4 * 8];
  __syncthreads();
  f32x4 acc = {};
#pragma unroll
  for (int kk = 0; kk < 16; ++kk) {
    short8 bfr = *(const short8*)&w2t[l15 * 520 + kk * 32 + l4 * 8];
    acc = __builtin_amdgcn_mfma_f32_16x16x32_bf16(af[kk], bfr, acc, 0, 0, 0);
  }
#pragma unroll
  for (int j = 0; j < 4; ++j) {
    int r = r0 + l4 * 4 + j;
    if (r < NNODES) t2[(size_t)r * NCLS + l15] = acc[j];
  }
}

// ---------- spmm2 + bias, unroll x4, packed edge records ----------
__global__ __launch_bounds__(256) void k_spmm2(const int* __restrict__ rs,
                                               const int2* __restrict__ evec,
                                               const float* __restrict__ t2,
                                               const float* __restrict__ b2,
                                               float* __restrict__ out) {
  int t = threadIdx.x;
  int f = t & 15, rl = t >> 4;
  int r = blockIdx.x * 16 + rl;
  if (r >= NNODES) return;
  const char* t2b = (const char*)t2 + f * 4;
  int e0 = rs[r], e1 = rs[r + 1];
  float a0 = 0.f, a1 = 0.f, a2 = 0.f, a3 = 0.f;
  int e = e0;
  for (; e + 3 < e1; e += 4) {
    int2 v0 = evec[e], v1 = evec[e + 1], v2 = evec[e + 2], v3 = evec[e + 3];
    a0 += __int_as_float(v0.y) * *(const float*)(t2b + (size_t)(unsigned)(v0.x >> 1));
    a1 += __int_as_float(v1.y) * *(const float*)(t2b + (size_t)(unsigned)(v1.x >> 1));
    a2 += __int_as_float(v2.y) * *(const float*)(t2b + (size_t)(unsigned)(v2.x >> 1));
    a3 += __int_as_float(v3.y) * *(const float*)(t2b + (size_t)(unsigned)(v3.x >> 1));
  }
  for (; e < e1; ++e) {
    int2 v = evec[e];
    a0 += __int_as_float(v.y) * *(const float*)(t2b + (size_t)(unsigned)(v.x >> 1));
  }
  out[(size_t)r * NCLS + f] = (a0 + a1) + (a2 + a3) + b2[f];
}

extern "C" void kernel_launch(void* const* d_in, const int* in_sizes, int n_in,
                              void* d_out, int out_size, void* d_ws, size_t ws_size,
                              hipStream_t stream) {
  (void)in_sizes; (void)n_in; (void)out_size; (void)ws_size;
  const int*   x    = (const int*)  d_in[0];
  const int*   rows = (const int*)  d_in[1];
  const int*   cols = (const int*)  d_in[2];
  const float* vals = (const float*)d_in[3];
  const float* emb  = (const float*)d_in[4];
  const float* W1   = (const float*)d_in[5];
  const float* b1   = (const float*)d_in[6];
  const float* W2   = (const float*)d_in[7];
  const float* b2   = (const float*)d_in[8];
  float* out = (float*)d_out;

  char* ws = (char*)d_ws;
  size_t off = 0;
  auto take = [&](size_t bytes) {
    char* p = ws + off;
    off = (off + bytes + 255) & ~(size_t)255;
    return p;
  };
  unsigned short* embr = (unsigned short*)take((size_t)EMBROWS * 128 * 2);
  unsigned short* w1t  = (unsigned short*)take((size_t)NHID * INCH * 2);
  unsigned short* t1s  = (unsigned short*)take((size_t)NNODES * NHID * 2);
  unsigned short* h1   = (unsigned short*)take((size_t)NNODES * NHID * 2);
  float*          t2   = (float*)take((size_t)NNODES * NCLS * 4);
  int*            counts = (int*)take((size_t)2 * NNODES * 4);   // counts + cursor adjacent
  int*            cursor = counts + NNODES;
  int*            rs     = (int*)take((size_t)(NNODES + 1) * 4);
  int2*           evec   = (int2*)take((size_t)NEDGE * 8);

  hipMemsetAsync(counts, 0, (size_t)2 * NNODES * 4, stream);

  k_prep<<<NB_EMBR + NB_W1T + NB_HIST, 256, 0, stream>>>(emb, embr, W1, w1t, rows, counts);
  k_scan<<<1, 1024, 0, stream>>>(counts, rs);
  k_scatter<<<(NEDGE + 255) / 256, 256, 0, stream>>>(rows, cols, vals, rs, cursor, evec);
  k_gemm1<<<((NNODES + 127) / 128) * 8, 256, 0, stream>>>(x, embr, w1t, t1s);
  k_spmm1<<<((NNODES + 15) / 16) * 8, 256, 0, stream>>>(rs, evec, t1s, b1, h1);
  k_gemm2<<<(NNODES + 63) / 64, 256, 0, stream>>>(h1, W2, t2);
  k_spmm2<<<(NNODES + 15) / 16, 256, 0, stream>>>(rs, evec, t2, b2, out);
}

// Round 10
// 141.914 us; speedup vs baseline: 1.3109x; 1.0930x over previous
//
#include <hip/hip_runtime.h>

#define NNODES 15279
#define NEDGE  488928
#define INCH   1024
#define NHID   512
#define NCLS   16
#define EMBROWS 10001

#define NB_EMBR 1251   // ceil(10001*128/4 / 256)
#define NB_W1T  128    // 16 k-tiles x 8 n-tiles
#define NB_HIST 1910   // ceil(488928/256)
#define NB_GEMM1 960   // 120 m-tiles x 8 n-tiles
#define NB_SCAT 1910

using short8 = __attribute__((ext_vector_type(8))) short;
using f32x4  = __attribute__((ext_vector_type(4))) float;
using f32x2  = __attribute__((ext_vector_type(2))) float;

__device__ __forceinline__ float bf2f(unsigned short u) {
  union { unsigned int i; float f; } v; v.i = ((unsigned int)u) << 16; return v.f;
}
__device__ __forceinline__ float asf(unsigned int u) {
  union { unsigned int i; float f; } v; v.i = u; return v.f;
}
__device__ __forceinline__ unsigned short f2bf(float f) {
  union { float ff; unsigned int i; } v; v.ff = f;
  return (unsigned short)((v.i + 0x7FFFu + ((v.i >> 16) & 1u)) >> 16);
}

// ---------- prep: relu(emb)->bf16 embr  |  W1 transpose->bf16  |  edge histogram ----------
__global__ __launch_bounds__(256) void k_prep(const float* __restrict__ emb,
                                              unsigned short* __restrict__ embr,
                                              const float* __restrict__ W1,
                                              unsigned short* __restrict__ w1t,
                                              const int* __restrict__ rows,
                                              int* __restrict__ counts) {
  __shared__ float tile[64][65];
  int b = blockIdx.x;
  int t = threadIdx.x;
  if (b < NB_EMBR) {
    int g = b * 256 + t;
    if (g * 4 < EMBROWS * 128) {
      const float4 v = *(const float4*)&emb[g * 4];
      unsigned int lo = (unsigned int)f2bf(fmaxf(v.x, 0.f)) | ((unsigned int)f2bf(fmaxf(v.y, 0.f)) << 16);
      unsigned int hi = (unsigned int)f2bf(fmaxf(v.z, 0.f)) | ((unsigned int)f2bf(fmaxf(v.w, 0.f)) << 16);
      uint2 o; o.x = lo; o.y = hi;
      *(uint2*)&embr[g * 4] = o;
    }
  } else if (b < NB_EMBR + NB_W1T) {
    int b2 = b - NB_EMBR;
    int k0 = (b2 & 15) * 64, n0 = (b2 >> 4) * 64;
    int c = t & 63, r4 = t >> 6;
    for (int i = 0; i < 16; ++i) {
      int r = r4 + i * 4;
      tile[r][c] = W1[(k0 + r) * NHID + n0 + c];
    }
    __syncthreads();
    for (int i = 0; i < 16; ++i) {
      int nr = r4 + i * 4;
      w1t[(size_t)(n0 + nr) * INCH + k0 + c] = f2bf(tile[c][nr]);
    }
  } else {
    int e = (b - NB_EMBR - NB_W1T) * 256 + t;
    if (e < NEDGE) atomicAdd(&counts[rows[e]], 1);
  }
}

// ---------- exclusive scan, 1024 threads x 15 elems ----------
__global__ __launch_bounds__(1024) void k_scan(const int* __restrict__ counts,
                                               int* __restrict__ rs) {
  int t = threadIdx.x;
  int lo = t * 15, hi = lo + 15;
  if (hi > NNODES) hi = NNODES;
  if (lo > NNODES) lo = NNODES;
  int s = 0;
  for (int i = lo; i < hi; ++i) s += counts[i];
  int lane = t & 63, wid = t >> 6;
  int v = s;
  for (int d = 1; d < 64; d <<= 1) {
    int u = __shfl_up(v, d);
    if (lane >= d) v += u;
  }
  __shared__ int wsum[16];
  if (lane == 63) wsum[wid] = v;
  __syncthreads();
  int wbase = 0;
  for (int w2 = 0; w2 < wid; ++w2) wbase += wsum[w2];
  int run = wbase + v - s;
  for (int i = lo; i < hi; ++i) { rs[i] = run; run += counts[i]; }
  if (t == 1023) rs[NNODES] = run;
}

// ---------- GEMM1 (blocks 0..959) + SCATTER (blocks 960..2869), one launch ----------
// The two are mutually independent (gemm1 needs prep; scatter needs scan) and
// use disjoint pipes (MFMA vs latency-bound atomics) -> scatter rides free.
__global__ __launch_bounds__(256) void k_gemm1_scatter(
    const int* __restrict__ x,
    const unsigned short* __restrict__ embr,
    const unsigned short* __restrict__ Bt,
    unsigned short* __restrict__ Cs,
    const int* __restrict__ rows,
    const int* __restrict__ cols,
    const float* __restrict__ vals,
    const int* __restrict__ rs,
    int* __restrict__ cursor,
    int2* __restrict__ evec) {
  __shared__ unsigned short As[128 * 64];
  __shared__ unsigned short Bs[64 * 64];
  const int t = threadIdx.x;
  if (blockIdx.x >= NB_GEMM1) {
    int e = (blockIdx.x - NB_GEMM1) * 256 + t;
    if (e < NEDGE) {
      int r = rows[e];
      int p = rs[r] + atomicAdd(&cursor[r], 1);
      int2 ev; ev.x = cols[e] * 128; ev.y = __float_as_int(vals[e]);
      evec[p] = ev;
    }
    return;
  }
  const int m0 = (blockIdx.x >> 3) * 128;
  const int n0 = (blockIdx.x & 7) * 64;
  const int w = t >> 6, l = t & 63;
  const int wm = w >> 1, wn = w & 1;
  const int l4 = l >> 4, l15 = l & 15;
  const int rowA = wm * 64 + l15;
  const int colB = wn * 32 + l15;
  f32x4 acc[4][2] = {};

  int xidx[4][8];
#pragma unroll
  for (int i = 0; i < 4; ++i) {
    int grow = m0 + (t >> 3) + i * 32;
    grow = grow < NNODES ? grow : NNODES - 1;
    *(int4*)&xidx[i][0] = *(const int4*)&x[grow * 8];
    *(int4*)&xidx[i][4] = *(const int4*)&x[grow * 8 + 4];
  }

#pragma unroll
  for (int kt = 0; kt < 16; ++kt) {
    const int k0 = kt * 64;
    const int s = kt >> 1;
    const int dbase = (kt & 1) * 64;
#pragma unroll
    for (int i = 0; i < 4; ++i) {
      int p = i * 256 + t;
      int row = i * 32 + (t >> 3);
      int skg = ((t & 7) ^ (row & 7)) * 8;
      __builtin_amdgcn_global_load_lds(
          (const __attribute__((address_space(1))) void*)&embr[(size_t)xidx[i][s] * 128 + dbase + skg],
          (__attribute__((address_space(3))) void*)&As[p * 8], 16, 0, 0);
    }
#pragma unroll
    for (int i = 0; i < 2; ++i) {
      int p = i * 256 + t;
      int row = i * 32 + (t >> 3);
      int skg = ((t & 7) ^ (row & 7)) * 8;
      __builtin_amdgcn_global_load_lds(
          (const __attribute__((address_space(1))) void*)&Bt[(size_t)(n0 + row) * INCH + k0 + skg],
          (__attribute__((address_space(3))) void*)&Bs[p * 8], 16, 0, 0);
    }
    __syncthreads();
#pragma unroll
    for (int kk = 0; kk < 2; ++kk) {
      short8 af[4], bfr[2];
#pragma unroll
      for (int m = 0; m < 4; ++m) {
        int r = rowA + m * 16;
        af[m] = *(const short8*)&As[(r * 8 + ((kk * 4 + l4) ^ (r & 7))) * 8];
      }
#pragma unroll
      for (int n = 0; n < 2; ++n) {
        int c = colB + n * 16;
        bfr[n] = *(const short8*)&Bs[(c * 8 + ((kk * 4 + l4) ^ (c & 7))) * 8];
      }
#pragma unroll
      for (int m = 0; m < 4; ++m)
#pragma unroll
        for (int n = 0; n < 2; ++n)
          acc[m][n] = __builtin_amdgcn_mfma_f32_16x16x32_bf16(af[m], bfr[n], acc[m][n], 0, 0, 0);
    }
    __syncthreads();
  }
  const int rb = m0 + wm * 64 + l4 * 4;
  const int cb = wn * 32 + l15;
  unsigned short* Cb = Cs + (size_t)(n0 >> 6) * NNODES * 64;
#pragma unroll
  for (int m = 0; m < 4; ++m)
#pragma unroll
    for (int j = 0; j < 4; ++j) {
      int r = rb + m * 16 + j;
      if (r < NNODES) {
        Cb[(size_t)r * 64 + cb]      = f2bf(acc[m][0][j]);
        Cb[(size_t)r * 64 + cb + 16] = f2bf(acc[m][1][j]);
      }
    }
}

// ---------- spmm1 + bias + relu, feature-sliced, 4 rows/warp x 2 edge-lanes ----------
// Edge-lane split is BLOCKED (el=0: first half, el=1: second half) so each
// lane's evec reads are adjacent; unroll x8 -> 8 independent gathers in flight.
__global__ __launch_bounds__(256) void k_spmm1(const int* __restrict__ rs,
                                               const int2* __restrict__ evec,
                                               const unsigned short* __restrict__ t1s,
                                               const float* __restrict__ b1,
                                               unsigned short* __restrict__ h1) {
  int b = blockIdx.x;
  int slice = b & 7;
  int rgrp = b >> 3;
  int t = threadIdx.x;
  int wid = t >> 6, lane = t & 63;
  int rloc = lane >> 4, el = (lane >> 3) & 1, ft = lane & 7;
  int r = rgrp * 16 + wid * 4 + rloc;
  bool valid = r < NNODES;
  int rr = valid ? r : NNODES - 1;
  const char* tbase = (const char*)(t1s + (size_t)slice * NNODES * 64) + ft * 16;
  int fglob = slice * 64 + ft * 8;
  int e0 = rs[rr];
  int e1 = valid ? rs[rr + 1] : e0;
  int half = (e1 - e0 + 1) >> 1;
  int eb = el ? e0 + half : e0;
  int ee = el ? e1 : e0 + half;
  f32x2 acc[4] = {};
  int e = eb;
  for (; e + 7 < ee; e += 8) {
    int2 ev0 = evec[e],     ev1 = evec[e + 1], ev2 = evec[e + 2], ev3 = evec[e + 3];
    int2 ev4 = evec[e + 4], ev5 = evec[e + 5], ev6 = evec[e + 6], ev7 = evec[e + 7];
    uint4 q0 = *(const uint4*)(tbase + (size_t)(unsigned)ev0.x);
    uint4 q1 = *(const uint4*)(tbase + (size_t)(unsigned)ev1.x);
    uint4 q2 = *(const uint4*)(tbase + (size_t)(unsigned)ev2.x);
    uint4 q3 = *(const uint4*)(tbase + (size_t)(unsigned)ev3.x);
    uint4 q4 = *(const uint4*)(tbase + (size_t)(unsigned)ev4.x);
    uint4 q5 = *(const uint4*)(tbase + (size_t)(unsigned)ev5.x);
    uint4 q6 = *(const uint4*)(tbase + (size_t)(unsigned)ev6.x);
    uint4 q7 = *(const uint4*)(tbase + (size_t)(unsigned)ev7.x);
#pragma unroll
    for (int i = 0; i < 8; ++i) {
      int2  ev = i == 0 ? ev0 : i == 1 ? ev1 : i == 2 ? ev2 : i == 3 ? ev3
               : i == 4 ? ev4 : i == 5 ? ev5 : i == 6 ? ev6 : ev7;
      uint4 q  = i == 0 ? q0  : i == 1 ? q1  : i == 2 ? q2  : i == 3 ? q3
               : i == 4 ? q4  : i == 5 ? q5  : i == 6 ? q6  : q7;
      float v = __int_as_float(ev.y);
      f32x2 vv = {v, v};
      unsigned int u[4] = {q.x, q.y, q.z, q.w};
#pragma unroll
      for (int d = 0; d < 4; ++d) {
        f32x2 p = {asf(u[d] << 16), asf(u[d] & 0xffff0000u)};
        acc[d] += vv * p;
      }
    }
  }
  for (; e + 3 < ee; e += 4) {
    int2 ev0 = evec[e], ev1 = evec[e + 1], ev2 = evec[e + 2], ev3 = evec[e + 3];
    uint4 q0 = *(const uint4*)(tbase + (size_t)(unsigned)ev0.x);
    uint4 q1 = *(const uint4*)(tbase + (size_t)(unsigned)ev1.x);
    uint4 q2 = *(const uint4*)(tbase + (size_t)(unsigned)ev2.x);
    uint4 q3 = *(const uint4*)(tbase + (size_t)(unsigned)ev3.x);
    float v0 = __int_as_float(ev0.y), v1 = __int_as_float(ev1.y);
    float v2 = __int_as_float(ev2.y), v3 = __int_as_float(ev3.y);
    f32x2 w0 = {v0, v0}, w1 = {v1, v1}, w2 = {v2, v2}, w3 = {v3, v3};
    unsigned int u0[4] = {q0.x, q0.y, q0.z, q0.w};
    unsigned int u1[4] = {q1.x, q1.y, q1.z, q1.w};
    unsigned int u2[4] = {q2.x, q2.y, q2.z, q2.w};
    unsigned int u3[4] = {q3.x, q3.y, q3.z, q3.w};
#pragma unroll
    for (int d = 0; d < 4; ++d) {
      f32x2 p0 = {asf(u0[d] << 16), asf(u0[d] & 0xffff0000u)};
      f32x2 p1 = {asf(u1[d] << 16), asf(u1[d] & 0xffff0000u)};
      f32x2 p2 = {asf(u2[d] << 16), asf(u2[d] & 0xffff0000u)};
      f32x2 p3 = {asf(u3[d] << 16), asf(u3[d] & 0xffff0000u)};
      acc[d] += w0 * p0;
      acc[d] += w1 * p1;
      acc[d] += w2 * p2;
      acc[d] += w3 * p3;
    }
  }
  for (; e < ee; ++e) {
    int2 ev = evec[e];
    uint4 a = *(const uint4*)(tbase + (size_t)(unsigned)ev.x);
    float v = __int_as_float(ev.y);
    f32x2 v2 = {v, v};
    unsigned int ua[4] = {a.x, a.y, a.z, a.w};
#pragma unroll
    for (int d = 0; d < 4; ++d) {
      f32x2 p = {asf(ua[d] << 16), asf(ua[d] & 0xffff0000u)};
      acc[d] += v2 * p;
    }
  }
#pragma unroll
  for (int d = 0; d < 4; ++d) {
    acc[d].x += __shfl_xor(acc[d].x, 8);
    acc[d].y += __shfl_xor(acc[d].y, 8);
  }
  if (el == 0 && valid) {
    unsigned int o[4];
#pragma unroll
    for (int d = 0; d < 4; ++d) {
      float s0 = fmaxf(acc[d].x + b1[fglob + 2 * d], 0.f);
      float s1 = fmaxf(acc[d].y + b1[fglob + 2 * d + 1], 0.f);
      o[d] = (unsigned int)f2bf(s0) | ((unsigned int)f2bf(s1) << 16);
    }
    uint4 ov; ov.x = o[0]; ov.y = o[1]; ov.z = o[2]; ov.w = o[3];
    *(uint4*)&h1[(size_t)r * NHID + fglob] = ov;
  }
}

// ---------- GEMM2: t2 = h1 @ W2  (MFMA, all 16 A-fragments prefetched) ----------
__global__ __launch_bounds__(256) void k_gemm2(const unsigned short* __restrict__ h1,
                                               const float* __restrict__ W2,
                                               float* __restrict__ t2) {
  __shared__ unsigned short w2t[16 * 520];
  int t = threadIdx.x;
#pragma unroll
  for (int i = 0; i < 32; ++i) {
    int p = i * 256 + t;
    int k = p >> 4, f = p & 15;
    w2t[f * 520 + k] = f2bf(W2[p]);
  }
  int w = t >> 6, l = t & 63;
  int l15 = l & 15, l4 = l >> 4;
  int r0 = blockIdx.x * 64 + w * 16;
  int row = r0 + l15; row = row < NNODES ? row : NNODES - 1;
  short8 af[16];
#pragma unroll
  for (int kk = 0; kk < 16; ++kk)
    af[kk] = *(const short8*)&h1[(size_t)row * NHID + kk * 32 + l4 * 8];
  __syncthreads();
  f32x4 acc = {};
#pragma unroll
  for (int kk = 0; kk < 16; ++kk) {
    short8 bfr = *(const short8*)&w2t[l15 * 520 + kk * 32 + l4 * 8];
    acc = __builtin_amdgcn_mfma_f32_16x16x32_bf16(af[kk], bfr, acc, 0, 0, 0);
  }
#pragma unroll
  for (int j = 0; j < 4; ++j) {
    int r = r0 + l4 * 4 + j;
    if (r < NNODES) t2[(size_t)r * NCLS + l15] = acc[j];
  }
}

// ---------- spmm2 + bias, unroll x4, packed edge records ----------
__global__ __launch_bounds__(256) void k_spmm2(const int* __restrict__ rs,
                                               const int2* __restrict__ evec,
                                               const float* __restrict__ t2,
                                               const float* __restrict__ b2,
                                               float* __restrict__ out) {
  int t = threadIdx.x;
  int f = t & 15, rl = t >> 4;
  int r = blockIdx.x * 16 + rl;
  if (r >= NNODES) return;
  const char* t2b = (const char*)t2 + f * 4;
  int e0 = rs[r], e1 = rs[r + 1];
  float a0 = 0.f, a1 = 0.f, a2 = 0.f, a3 = 0.f;
  int e = e0;
  for (; e + 3 < e1; e += 4) {
    int2 v0 = evec[e], v1 = evec[e + 1], v2 = evec[e + 2], v3 = evec[e + 3];
    a0 += __int_as_float(v0.y) * *(const float*)(t2b + (size_t)(unsigned)(v0.x >> 1));
    a1 += __int_as_float(v1.y) * *(const float*)(t2b + (size_t)(unsigned)(v1.x >> 1));
    a2 += __int_as_float(v2.y) * *(const float*)(t2b + (size_t)(unsigned)(v2.x >> 1));
    a3 += __int_as_float(v3.y) * *(const float*)(t2b + (size_t)(unsigned)(v3.x >> 1));
  }
  for (; e < e1; ++e) {
    int2 v = evec[e];
    a0 += __int_as_float(v.y) * *(const float*)(t2b + (size_t)(unsigned)(v.x >> 1));
  }
  out[(size_t)r * NCLS + f] = (a0 + a1) + (a2 + a3) + b2[f];
}

extern "C" void kernel_launch(void* const* d_in, const int* in_sizes, int n_in,
                              void* d_out, int out_size, void* d_ws, size_t ws_size,
                              hipStream_t stream) {
  (void)in_sizes; (void)n_in; (void)out_size; (void)ws_size;
  const int*   x    = (const int*)  d_in[0];
  const int*   rows = (const int*)  d_in[1];
  const int*   cols = (const int*)  d_in[2];
  const float* vals = (const float*)d_in[3];
  const float* emb  = (const float*)d_in[4];
  const float* W1   = (const float*)d_in[5];
  const float* b1   = (const float*)d_in[6];
  const float* W2   = (const float*)d_in[7];
  const float* b2   = (const float*)d_in[8];
  float* out = (float*)d_out;

  char* ws = (char*)d_ws;
  size_t off = 0;
  auto take = [&](size_t bytes) {
    char* p = ws + off;
    off = (off + bytes + 255) & ~(size_t)255;
    return p;
  };
  unsigned short* embr = (unsigned short*)take((size_t)EMBROWS * 128 * 2);
  unsigned short* w1t  = (unsigned short*)take((size_t)NHID * INCH * 2);
  unsigned short* t1s  = (unsigned short*)take((size_t)NNODES * NHID * 2);
  unsigned short* h1   = (unsigned short*)take((size_t)NNODES * NHID * 2);
  float*          t2   = (float*)take((size_t)NNODES * NCLS * 4);
  int*            counts = (int*)take((size_t)2 * NNODES * 4);   // counts + cursor adjacent
  int*            cursor = counts + NNODES;
  int*            rs     = (int*)take((size_t)(NNODES + 1) * 4);
  int2*           evec   = (int2*)take((size_t)NEDGE * 8);

  hipMemsetAsync(counts, 0, (size_t)2 * NNODES * 4, stream);

  k_prep<<<NB_EMBR + NB_W1T + NB_HIST, 256, 0, stream>>>(emb, embr, W1, w1t, rows, counts);
  k_scan<<<1, 1024, 0, stream>>>(counts, rs);
  k_gemm1_scatter<<<NB_GEMM1 + NB_SCAT, 256, 0, stream>>>(x, embr, w1t, t1s,
                                                          rows, cols, vals, rs, cursor, evec);
  k_spmm1<<<((NNODES + 15) / 16) * 8, 256, 0, stream>>>(rs, evec, t1s, b1, h1);
  k_gemm2<<<(NNODES + 63) / 64, 256, 0, stream>>>(h1, W2, t2);
  k_spmm2<<<(NNODES + 15) / 16, 256, 0, stream>>>(rs, evec, t2, b2, out);
}